// Round 7
// baseline (491.942 us; speedup 1.0000x reference)
//
#include <hip/hip_runtime.h>
#include <hip/hip_bf16.h>
#include <cstdint>
#include <cstddef>

#define TOKENS 4096
#define DM     1024
#define DFF    4096
#define NE     15     // router experts
#define DFR    2048   // router expert hidden (and shared half)
#define NEX    17     // 15 router + 2 shared halves
#define MAXT   104    // max 256-row M-tiles (bound: 12288/256 + 15 partial + 32 shared <= 103)

typedef float f32x4 __attribute__((ext_vector_type(4)));
typedef int   i32x4 __attribute__((ext_vector_type(4)));

__device__ __forceinline__ void mfma_16x16x32_bf16(f32x4& d, i32x4 a, i32x4 b){
  asm("v_mfma_f32_16x16x32_bf16 %0, %1, %2, %0" : "+v"(d) : "v"(a), "v"(b));
}

__device__ __forceinline__ void gload16(const void* g, void* l){
  __builtin_amdgcn_global_load_lds(
      (const __attribute__((address_space(1))) uint32_t*)g,
      (__attribute__((address_space(3))) uint32_t*)l, 16, 0, 0);
}

__device__ __forceinline__ unsigned short f2bf(float f){
  unsigned u = __float_as_uint(f);
  u += 0x7FFFu + ((u >> 16) & 1u);      // round-to-nearest-even
  return (unsigned short)(u >> 16);
}

__device__ __forceinline__ float gelu_exact(float v){
  return 0.5f * v * (1.0f + erff(v * 0.70710678118654752440f));
}

// ---------------- prep kernels ----------------

__global__ void cast_x_kernel(const float* __restrict__ x, ushort* __restrict__ xb, int n4){
  int i = blockIdx.x*256 + threadIdx.x;
  if (i >= n4) return;
  float4 v = reinterpret_cast<const float4*>(x)[i];
  ushort4 o; o.x=f2bf(v.x); o.y=f2bf(v.y); o.z=f2bf(v.z); o.w=f2bf(v.w);
  reinterpret_cast<ushort4*>(xb)[i] = o;
}

// src [batch][R][C] f32 -> dst [batch][C][R] bf16
__global__ void tcast_kernel(const float* __restrict__ src, ushort* __restrict__ dst, int R, int C){
  __shared__ float tile[32][33];
  const size_t bo = (size_t)blockIdx.z * R * C;
  const int c0 = blockIdx.x*32, r0 = blockIdx.y*32;
  const int tx = threadIdx.x, ty = threadIdx.y;
  #pragma unroll
  for (int i=0;i<4;i++){
    int r = ty + i*8;
    tile[r][tx] = src[bo + (size_t)(r0+r)*C + c0 + tx];
  }
  __syncthreads();
  #pragma unroll
  for (int i=0;i<4;i++){
    int r = ty + i*8;
    dst[bo + (size_t)(c0+r)*R + r0 + tx] = f2bf(tile[tx][r]);
  }
}

// ---------------- gating (phase A: per-token top-3, NO atomics) ----------------

__global__ void gate_kernel(const float* __restrict__ x, const float* __restrict__ gW,
                            const float* __restrict__ gb,
                            int* __restrict__ tokexp, float* __restrict__ tokp){
  const int wave = threadIdx.x >> 6, lane = threadIdx.x & 63;
  const int token = blockIdx.x*4 + wave;
  const float* xr = x + (size_t)token * DM;
  float a[NE];
  #pragma unroll
  for (int e=0;e<NE;e++) a[e] = 0.f;
  const int d0 = lane * 16;
  float xv[16];
  #pragma unroll
  for (int j=0;j<4;j++){
    float4 v = reinterpret_cast<const float4*>(xr + d0)[j];
    xv[j*4+0]=v.x; xv[j*4+1]=v.y; xv[j*4+2]=v.z; xv[j*4+3]=v.w;
  }
  for (int j=0;j<16;j++){
    const float* gr = gW + (size_t)(d0 + j) * NE;
    #pragma unroll
    for (int e=0;e<NE;e++) a[e] += xv[j]*gr[e];
  }
  #pragma unroll
  for (int e=0;e<NE;e++){
    for (int off=32; off; off>>=1) a[e] += __shfl_xor(a[e], off, 64);
  }
  if (lane == 0){
    float l[NE], p[NE];
    float m = -1e30f;
    for (int e=0;e<NE;e++){ l[e] = a[e] + gb[e]; m = fmaxf(m, l[e]); }
    float s = 0.f;
    for (int e=0;e<NE;e++){ p[e] = expf(l[e]-m); s += p[e]; }
    float inv = 1.f/s;
    unsigned used = 0;
    for (int k=0;k<3;k++){
      int best = -1; float bv = -1e30f;
      for (int e=0;e<NE;e++) if (!((used>>e)&1u) && l[e] > bv){ bv = l[e]; best = e; }
      used |= 1u<<best;
      tokexp[token*3 + k] = best;
      tokp[token*3 + k]   = p[best]*inv;
    }
  }
}

// ---------------- gating (phase B: deterministic slot assignment, 1 block) ----

__global__ void assign_kernel(const int* __restrict__ tokexp, const float* __restrict__ tokp,
                              int* __restrict__ counts, int* __restrict__ bases,
                              int* __restrict__ tokidx, float* __restrict__ gatev,
                              int* __restrict__ tokslot,
                              int* __restrict__ tile_e, int* __restrict__ tile_by,
                              int* __restrict__ ntiles){
  __shared__ int lh[256][NE];      // per-thread-chunk histogram
  const int tid = threadIdx.x;
  const int t0 = tid * 16;

  int le[48];                      // this chunk's expert picks (16 tokens x 3)
  #pragma unroll
  for (int e=0;e<NE;e++) lh[tid][e] = 0;
  #pragma unroll
  for (int j=0;j<48;j++){
    int e = tokexp[t0*3 + j];
    le[j] = e;
    lh[tid][e]++;
  }
  __syncthreads();
  // per-expert exclusive scan over the 256 chunks (serial per expert; 15 threads)
  if (tid < NE){
    int run = 0;
    for (int i=0;i<256;i++){
      int v = lh[i][tid];
      lh[i][tid] = run;
      run += v;
    }
    counts[tid] = run;
  }
  __syncthreads();
  if (tid == 0){
    int b = 0;
    int t = 0;
    for (int e=0;e<NE;e++){
      int c = counts[e];
      int prows = ((c+127)>>7)<<7;        // 128-aligned padded rows (hbuf layout)
      bases[e] = b; b += prows;
      int nb = (prows + 255) >> 8;        // 256-row GEMM M-tiles
      for (int j=0;j<nb && t<MAXT;j++){ tile_e[t]=e; tile_by[t]=j; t++; }
    }
    bases[NE] = b; bases[NE+1] = b + TOKENS;
    for (int e=NE;e<NEX;e++){
      for (int j=0;j<16 && t<MAXT;j++){ tile_e[t]=e; tile_by[t]=j; t++; }
    }
    ntiles[0] = t;
  }
  __syncthreads();
  // re-walk: assign slots in token order (deterministic)
  #pragma unroll
  for (int j=0;j<48;j++){
    const int t = t0 + (j/3), k = j - (j/3)*3;
    const int e = le[j];
    const int slot = lh[tid][e]++;
    const int idx = e*TOKENS + slot;
    tokidx[idx] = t;
    gatev[idx]  = tokp[t*3 + k];
    tokslot[t*3 + k] = idx;
  }
}

// ---------------- 256x256x64 8-wave grouped GEMM core pieces ----------------
// LDS: 2 buffers x {A[256][64], B[256][64]} bf16 = 128 KiB. Linear store via
// global_load_lds (dest = uniform + lane*16); T2 swizzle applied as the SAME
// involution on the per-lane GLOBAL source and on the ds_read address
// (col_byte ^= (row&7)<<4) -- rule #21 both-sides.
// Counted vmcnt: stage tile t+1, s_waitcnt vmcnt(8) (= tile t landed), barrier,
// compute 4 quadrant-phases (16 MFMA each, setprio-wrapped), barrier.

#define GEMM_COMPUTE(BASEB)                                                          \
  {                                                                                  \
    const char* gbase = (BASEB);                                                     \
    _Pragma("unroll")                                                                \
    for (int p=0; p<4; ++p){                                                         \
      const int qr = p>>1, qc = p&1;                                                 \
      i32x4 af[2][4], bf[2][2];                                                      \
      _Pragma("unroll")                                                              \
      for (int kk=0; kk<2; kk++){                                                    \
        const unsigned cb = (unsigned)((kk*64 + ((lane>>4)<<4)) ^ sw);               \
        _Pragma("unroll")                                                            \
        for (int m=0;m<4;m++){                                                       \
          const int row = wr*128 + qr*64 + m*16 + (lane&15);                         \
          af[kk][m] = *(const i32x4*)(gbase + row*128 + cb);                         \
        }                                                                            \
        _Pragma("unroll")                                                            \
        for (int n=0;n<2;n++){                                                       \
          const int row = wc*64 + qc*32 + n*16 + (lane&15);                          \
          bf[kk][n] = *(const i32x4*)(gbase + 32768 + row*128 + cb);                 \
        }                                                                            \
      }                                                                              \
      __builtin_amdgcn_s_setprio(1);                                                 \
      _Pragma("unroll")                                                              \
      for (int m=0;m<4;m++){                                                         \
        _Pragma("unroll")                                                            \
        for (int n=0;n<2;n++){                                                       \
          mfma_16x16x32_bf16(acc[qr*4+m][qc*2+n], af[0][m], bf[0][n]);               \
          mfma_16x16x32_bf16(acc[qr*4+m][qc*2+n], af[1][m], bf[1][n]);               \
        }                                                                            \
      }                                                                              \
      __builtin_amdgcn_s_setprio(0);                                                 \
    }                                                                                \
  }

#define GEMM_STAGE(BUF, T)                                                           \
  {                                                                                  \
    char* dA = smem + (size_t)(BUF)*65536;                                           \
    char* dB = dA + 32768;                                                           \
    _Pragma("unroll")                                                                \
    for (int i=0;i<4;i++){                                                           \
      gload16(aSrc[i] + (size_t)(T)*128, dA + i*8192 + tid*16);                      \
      gload16(bSrc[i] + (size_t)(T)*128, dB + i*8192 + tid*16);                      \
    }                                                                                \
  }

// ---------------- grouped GEMM 1: h = gelu(x @ W1 + b1) ----------------
// grid (8, MAXT), block 512. Tile 256x256, BK=64, NK=16.

__global__ __launch_bounds__(512,2) void gemm1_kernel(
    const ushort* __restrict__ xb, const ushort* __restrict__ rW1T,
    const ushort* __restrict__ sW1T, const float* __restrict__ rb1,
    const float* __restrict__ sb1, const int* __restrict__ counts,
    const int* __restrict__ bases, const int* __restrict__ tokidx,
    const int* __restrict__ tile_e, const int* __restrict__ tile_by,
    const int* __restrict__ ntiles, ushort* __restrict__ h)
{
  const int ty = blockIdx.y;
  if (ty >= ntiles[0]) return;
  const int e = tile_e[ty], by = tile_by[ty], bx = blockIdx.x;
  const int cnt = (e < NE) ? counts[e] : TOKENS;
  const int prows = (e < NE) ? (((cnt+127)>>7)<<7) : TOKENS;

  __shared__ __align__(16) char smem[131072];

  const int tid = threadIdx.x;            // 0..511
  const int wave = tid >> 6, lane = tid & 63;
  const int wr = wave >> 2, wc = wave & 3;
  const unsigned sw = (unsigned)((lane & 7) << 4);

  const char* Bpb = (e < NE) ? (const char*)rW1T + ((size_t)e*DFR)*2048
                             : (const char*)sW1T + ((size_t)(e-NE)*DFR)*2048;

  const unsigned scol = (unsigned)(((tid & 7) << 4) ^ (((tid >> 3) & 7) << 4));
  const char* aSrc[4];
  const char* bSrc[4];
  #pragma unroll
  for (int i=0;i<4;i++){
    const int rl = i*64 + (tid >> 3);
    const int gr = by*256 + rl;
    int tok;
    if (e < NE){ const int cr = gr < cnt ? gr : cnt-1; tok = tokidx[e*TOKENS + cr]; }
    else       { tok = gr < TOKENS ? gr : TOKENS-1; }
    aSrc[i] = (const char*)xb + (size_t)tok*2048 + scol;
    bSrc[i] = Bpb + (size_t)(bx*256 + rl)*2048 + scol;
  }

  f32x4 acc[8][4];
  #pragma unroll
  for (int m=0;m<8;m++){
    #pragma unroll
    for (int n=0;n<4;n++){ acc[m][n] = (f32x4){0.f,0.f,0.f,0.f}; }
  }

  const int NK = DM/64;   // 16
  GEMM_STAGE(0, 0);
  asm volatile("s_waitcnt vmcnt(0)" ::: "memory");
  __builtin_amdgcn_s_barrier();
  #pragma unroll 2
  for (int t=0; t<NK-1; ++t){
    GEMM_STAGE((t+1)&1, t+1);
    asm volatile("s_waitcnt vmcnt(8)" ::: "memory");
    __builtin_amdgcn_s_barrier();
    GEMM_COMPUTE(smem + (size_t)(t&1)*65536);
    __builtin_amdgcn_s_barrier();
  }
  asm volatile("s_waitcnt vmcnt(0)" ::: "memory");
  __builtin_amdgcn_s_barrier();
  GEMM_COMPUTE(smem + (size_t)((NK-1)&1)*65536);

  const int hb = bases[e];
  const float* b1p = (e < NE) ? (rb1 + e*DFR + bx*256) : (sb1 + (e-NE)*DFR + bx*256);
  #pragma unroll
  for (int m=0;m<8;m++){
    const int rt = wr*128 + m*16 + (lane>>4)*4;
    #pragma unroll
    for (int i=0;i<4;i++){
      const int gr = by*256 + rt + i;
      if (gr < prows){
        #pragma unroll
        for (int n=0;n<4;n++){
          const int c = wc*64 + n*16 + (lane & 15);
          float v = acc[m][n][i] + b1p[c];
          h[(size_t)(hb + gr)*DFR + (size_t)bx*256 + c] = f2bf(gelu_exact(v));
        }
      }
    }
  }
}

// ---------------- grouped GEMM 2: rout[row] = h @ W2 + b2 (bf16, no gate) ----
// grid (4, MAXT), block 512. Tile 256x256, BK=64, NK=32.

__global__ __launch_bounds__(512,2) void gemm2_kernel(
    const ushort* __restrict__ hbuf, const ushort* __restrict__ rW2T,
    const ushort* __restrict__ sW2T, const float* __restrict__ rb2,
    const float* __restrict__ sb2, const int* __restrict__ counts,
    const int* __restrict__ bases,
    const int* __restrict__ tile_e, const int* __restrict__ tile_by,
    const int* __restrict__ ntiles, ushort* __restrict__ rout)
{
  const int ty = blockIdx.y;
  if (ty >= ntiles[0]) return;
  const int e = tile_e[ty], by = tile_by[ty], bx = blockIdx.x;
  const int cnt = (e < NE) ? counts[e] : TOKENS;
  const int prows = (e < NE) ? (((cnt+127)>>7)<<7) : TOKENS;
  const int hb = bases[e];

  __shared__ __align__(16) char smem[131072];

  const int tid = threadIdx.x;
  const int wave = tid >> 6, lane = tid & 63;
  const int wr = wave >> 2, wc = wave & 3;
  const unsigned sw = (unsigned)((lane & 7) << 4);

  const unsigned scol = (unsigned)(((tid & 7) << 4) ^ (((tid >> 3) & 7) << 4));
  const char* aSrc[4];
  const char* bSrc[4];
  #pragma unroll
  for (int i=0;i<4;i++){
    const int rl = i*64 + (tid >> 3);
    int ar = by*256 + rl; if (ar >= prows) ar = prows-1;
    aSrc[i] = (const char*)hbuf + (size_t)(hb + ar)*4096 + scol;
    if (e < NE){
      bSrc[i] = (const char*)rW2T + ((size_t)e*DM + bx*256 + rl)*4096 + scol;
    } else {
      bSrc[i] = (const char*)sW2T + (size_t)(bx*256 + rl)*8192 + (size_t)(e-NE)*4096 + scol;
    }
  }

  f32x4 acc[8][4];
  #pragma unroll
  for (int m=0;m<8;m++){
    #pragma unroll
    for (int n=0;n<4;n++){ acc[m][n] = (f32x4){0.f,0.f,0.f,0.f}; }
  }

  const int NK = DFR/64;  // 32
  GEMM_STAGE(0, 0);
  asm volatile("s_waitcnt vmcnt(0)" ::: "memory");
  __builtin_amdgcn_s_barrier();
  #pragma unroll 2
  for (int t=0; t<NK-1; ++t){
    GEMM_STAGE((t+1)&1, t+1);
    asm volatile("s_waitcnt vmcnt(8)" ::: "memory");
    __builtin_amdgcn_s_barrier();
    GEMM_COMPUTE(smem + (size_t)(t&1)*65536);
    __builtin_amdgcn_s_barrier();
  }
  asm volatile("s_waitcnt vmcnt(0)" ::: "memory");
  __builtin_amdgcn_s_barrier();
  GEMM_COMPUTE(smem + (size_t)((NK-1)&1)*65536);

  #pragma unroll
  for (int m=0;m<8;m++){
    const int rt = wr*128 + m*16 + (lane>>4)*4;
    #pragma unroll
    for (int i=0;i<4;i++){
      const int gr = by*256 + rt + i;
      if (gr < prows){
        #pragma unroll
        for (int n=0;n<4;n++){
          const int c  = wc*64 + n*16 + (lane & 15);
          const int cg = bx*256 + c;
          const float bias = (e < NE) ? rb2[e*DM + cg] : ((e == NE) ? sb2[cg] : 0.f);
          rout[(size_t)(hb + gr)*DM + cg] = f2bf(acc[m][n][i] + bias);
        }
      }
    }
  }
}

// ---------------- combine: out = x + sh0 + sh1 + sum_k gate_k * rout ----------

__global__ void combine_kernel(const float* __restrict__ x, const ushort* __restrict__ rout,
                               const int* __restrict__ bases, const int* __restrict__ tokslot,
                               const float* __restrict__ gatev, float* __restrict__ out)
{
  const int wave = threadIdx.x >> 6, lane = threadIdx.x & 63;
  const int token = blockIdx.x*4 + wave;
  const int d0 = lane*16;

  float acc[16];
  #pragma unroll
  for (int j=0;j<4;j++){
    float4 v = reinterpret_cast<const float4*>(x + (size_t)token*DM + d0)[j];
    acc[j*4+0]=v.x; acc[j*4+1]=v.y; acc[j*4+2]=v.z; acc[j*4+3]=v.w;
  }

  int   rows[5];
  float gs[5];
  rows[0] = bases[NE]   + token; gs[0] = 1.f;
  rows[1] = bases[NE+1] + token; gs[1] = 1.f;
  #pragma unroll
  for (int k=0;k<3;k++){
    const int idx = tokslot[token*3 + k];
    const int e = idx >> 12, s = idx & (TOKENS-1);
    rows[2+k] = bases[e] + s;
    gs[2+k] = gatev[idx];
  }

  #pragma unroll
  for (int q=0;q<5;q++){
    const float g = gs[q];
    const ushort* rp = rout + (size_t)rows[q]*DM + d0;
    #pragma unroll
    for (int h=0;h<2;h++){
      i32x4 v = *reinterpret_cast<const i32x4*>(rp + h*8);
      #pragma unroll
      for (int j=0;j<4;j++){
        const unsigned u = (unsigned)v[j];
        acc[h*8 + j*2 + 0] += g * __uint_as_float(u << 16);
        acc[h*8 + j*2 + 1] += g * __uint_as_float(u & 0xFFFF0000u);
      }
    }
  }

  #pragma unroll
  for (int j=0;j<4;j++){
    float4 v; v.x=acc[j*4+0]; v.y=acc[j*4+1]; v.z=acc[j*4+2]; v.w=acc[j*4+3];
    reinterpret_cast<float4*>(out + (size_t)token*DM + d0)[j] = v;
  }
}

// ---------------- launcher ----------------

extern "C" void kernel_launch(void* const* d_in, const int* in_sizes, int n_in,
                              void* d_out, int out_size, void* d_ws, size_t ws_size,
                              hipStream_t stream)
{
  (void)in_sizes; (void)n_in; (void)out_size; (void)ws_size;
  const float* x   = (const float*)d_in[0];
  const float* sW1 = (const float*)d_in[1];
  const float* sb1 = (const float*)d_in[2];
  const float* sW2 = (const float*)d_in[3];
  const float* sb2 = (const float*)d_in[4];
  const float* rW1 = (const float*)d_in[5];
  const float* rb1 = (const float*)d_in[6];
  const float* rW2 = (const float*)d_in[7];
  const float* rb2 = (const float*)d_in[8];
  const float* gW  = (const float*)d_in[9];
  const float* gb  = (const float*)d_in[10];
  float* out = (float*)d_out;

  char* ws = (char*)d_ws;
  ushort* xb   = (ushort*)(ws + 0);          //  8,388,608  x bf16 [4096][1024]
  ushort* sW1T = (ushort*)(ws + 8388608);    //  8,388,608  [4096][1024]
  ushort* sW2T = (ushort*)(ws + 16777216);   //  8,388,608  [1024][4096]
  ushort* rW1T = (ushort*)(ws + 25165824);   // 62,914,560  [15][2048][1024]
  ushort* rW2T = (ushort*)(ws + 88080384);   // 62,914,560  [15][1024][2048]
  ushort* hbuf = (ushort*)(ws + 150994944);  // 92,274,688  [22528][2048]
  // rout ALIASES rW1T's region: rW1T is dead after gemm1, rout written by gemm2.
  ushort* rout = (ushort*)(ws + 25165824);   // 46,137,344  [22528][1024]
  int*   counts  = (int*)(ws + 243269632);
  int*   bases   = (int*)(ws + 243269760);
  int*   tokidx  = (int*)(ws + 243270144);   // 15*4096 ints
  float* gatev   = (float*)(ws + 243515904); // 15*4096 floats
  int*   tokslot = (int*)(ws + 243761664);   // 4096*3 ints
  int*   tokexp  = (int*)(ws + 243810816);   // 4096*3 ints
  float* tokp    = (float*)(ws + 243859968); // 4096*3 floats
  int*   tile_e  = (int*)(ws + 243909120);   // MAXT ints
  int*   tile_by = (int*)(ws + 243910144);   // MAXT ints
  int*   ntiles  = (int*)(ws + 243911168);   // 1 int
  // total ~244 MB of workspace

  cast_x_kernel<<<dim3(TOKENS*DM/4/256), dim3(256), 0, stream>>>(x, xb, TOKENS*DM/4);
  tcast_kernel<<<dim3(DFF/32, DM/32, 1),  dim3(32,8), 0, stream>>>(sW1, sW1T, DM, DFF);
  tcast_kernel<<<dim3(DM/32, DFF/32, 1),  dim3(32,8), 0, stream>>>(sW2, sW2T, DFF, DM);
  tcast_kernel<<<dim3(DFR/32, DM/32, NE), dim3(32,8), 0, stream>>>(rW1, rW1T, DM, DFR);
  tcast_kernel<<<dim3(DM/32, DFR/32, NE), dim3(32,8), 0, stream>>>(rW2, rW2T, DFR, DM);

  gate_kernel<<<dim3(TOKENS/4), dim3(256), 0, stream>>>(x, gW, gb, tokexp, tokp);
  assign_kernel<<<dim3(1), dim3(256), 0, stream>>>(tokexp, tokp, counts, bases,
                                                   tokidx, gatev, tokslot,
                                                   tile_e, tile_by, ntiles);

  gemm1_kernel<<<dim3(8,MAXT), dim3(512), 0, stream>>>(
      xb, rW1T, sW1T, rb1, sb1, counts, bases, tokidx, tile_e, tile_by, ntiles, hbuf);
  gemm2_kernel<<<dim3(4,MAXT), dim3(512), 0, stream>>>(
      hbuf, rW2T, sW2T, rb2, sb2, counts, bases, tile_e, tile_by, ntiles, rout);
  combine_kernel<<<dim3(TOKENS/4), dim3(256), 0, stream>>>(
      x, rout, bases, tokslot, gatev, out);
}

// Round 8
// 450.858 us; speedup vs baseline: 1.0911x; 1.0911x over previous
//
#include <hip/hip_runtime.h>
#include <hip/hip_bf16.h>
#include <cstdint>
#include <cstddef>

#define TOKENS 4096
#define DM     1024
#define DFF    4096
#define NE     15     // router experts
#define DFR    2048   // router expert hidden (and shared half)
#define NEX    17     // 15 router + 2 shared halves
#define MAXT   104    // 256-row M-tiles for gemm1
#define MAXT2  176    // 128-row M-tiles for gemm2

typedef float f32x4 __attribute__((ext_vector_type(4)));
typedef int   i32x4 __attribute__((ext_vector_type(4)));

__device__ __forceinline__ void mfma_16x16x32_bf16(f32x4& d, i32x4 a, i32x4 b){
  asm("v_mfma_f32_16x16x32_bf16 %0, %1, %2, %0" : "+v"(d) : "v"(a), "v"(b));
}

__device__ __forceinline__ void gload16(const void* g, void* l){
  __builtin_amdgcn_global_load_lds(
      (const __attribute__((address_space(1))) uint32_t*)g,
      (__attribute__((address_space(3))) uint32_t*)l, 16, 0, 0);
}

__device__ __forceinline__ unsigned short f2bf(float f){
  unsigned u = __float_as_uint(f);
  u += 0x7FFFu + ((u >> 16) & 1u);      // round-to-nearest-even
  return (unsigned short)(u >> 16);
}

__device__ __forceinline__ float gelu_exact(float v){
  return 0.5f * v * (1.0f + erff(v * 0.70710678118654752440f));
}

// ---------------- prep kernels ----------------

__global__ void cast_x_kernel(const float* __restrict__ x, ushort* __restrict__ xb, int n4){
  int i = blockIdx.x*256 + threadIdx.x;
  if (i >= n4) return;
  float4 v = reinterpret_cast<const float4*>(x)[i];
  ushort4 o; o.x=f2bf(v.x); o.y=f2bf(v.y); o.z=f2bf(v.z); o.w=f2bf(v.w);
  reinterpret_cast<ushort4*>(xb)[i] = o;
}

// src [batch][R][C] f32 -> dst [batch][C][R] bf16
__global__ void tcast_kernel(const float* __restrict__ src, ushort* __restrict__ dst, int R, int C){
  __shared__ float tile[32][33];
  const size_t bo = (size_t)blockIdx.z * R * C;
  const int c0 = blockIdx.x*32, r0 = blockIdx.y*32;
  const int tx = threadIdx.x, ty = threadIdx.y;
  #pragma unroll
  for (int i=0;i<4;i++){
    int r = ty + i*8;
    tile[r][tx] = src[bo + (size_t)(r0+r)*C + c0 + tx];
  }
  __syncthreads();
  #pragma unroll
  for (int i=0;i<4;i++){
    int r = ty + i*8;
    dst[bo + (size_t)(c0+r)*R + r0 + tx] = f2bf(tile[tx][r]);
  }
}

// ---------------- gating (phase A: per-token top-3, NO atomics) ----------------

__global__ void gate_kernel(const float* __restrict__ x, const float* __restrict__ gW,
                            const float* __restrict__ gb,
                            int* __restrict__ tokexp, float* __restrict__ tokp){
  const int wave = threadIdx.x >> 6, lane = threadIdx.x & 63;
  const int token = blockIdx.x*4 + wave;
  const float* xr = x + (size_t)token * DM;
  float a[NE];
  #pragma unroll
  for (int e=0;e<NE;e++) a[e] = 0.f;
  const int d0 = lane * 16;
  float xv[16];
  #pragma unroll
  for (int j=0;j<4;j++){
    float4 v = reinterpret_cast<const float4*>(xr + d0)[j];
    xv[j*4+0]=v.x; xv[j*4+1]=v.y; xv[j*4+2]=v.z; xv[j*4+3]=v.w;
  }
  for (int j=0;j<16;j++){
    const float* gr = gW + (size_t)(d0 + j) * NE;
    #pragma unroll
    for (int e=0;e<NE;e++) a[e] += xv[j]*gr[e];
  }
  #pragma unroll
  for (int e=0;e<NE;e++){
    for (int off=32; off; off>>=1) a[e] += __shfl_xor(a[e], off, 64);
  }
  if (lane == 0){
    float l[NE], p[NE];
    float m = -1e30f;
    for (int e=0;e<NE;e++){ l[e] = a[e] + gb[e]; m = fmaxf(m, l[e]); }
    float s = 0.f;
    for (int e=0;e<NE;e++){ p[e] = expf(l[e]-m); s += p[e]; }
    float inv = 1.f/s;
    unsigned used = 0;
    for (int k=0;k<3;k++){
      int best = -1; float bv = -1e30f;
      for (int e=0;e<NE;e++) if (!((used>>e)&1u) && l[e] > bv){ bv = l[e]; best = e; }
      used |= 1u<<best;
      tokexp[token*3 + k] = best;
      tokp[token*3 + k]   = p[best]*inv;
    }
  }
}

// ---------------- gating (phase B: deterministic slot assignment, 1 block) ----

__global__ void assign_kernel(const int* __restrict__ tokexp, const float* __restrict__ tokp,
                              int* __restrict__ counts, int* __restrict__ bases,
                              int* __restrict__ tokidx, float* __restrict__ gatev,
                              int* __restrict__ tokslot,
                              int* __restrict__ tile_e, int* __restrict__ tile_by,
                              int* __restrict__ tile2_e, int* __restrict__ tile2_by,
                              int* __restrict__ ntiles){
  __shared__ int lh[256][NE];      // per-thread-chunk histogram
  const int tid = threadIdx.x;
  const int t0 = tid * 16;

  int le[48];                      // this chunk's expert picks (16 tokens x 3)
  #pragma unroll
  for (int e=0;e<NE;e++) lh[tid][e] = 0;
  #pragma unroll
  for (int j=0;j<48;j++){
    int e = tokexp[t0*3 + j];
    le[j] = e;
    lh[tid][e]++;
  }
  __syncthreads();
  if (tid < NE){
    int run = 0;
    for (int i=0;i<256;i++){
      int v = lh[i][tid];
      lh[i][tid] = run;
      run += v;
    }
    counts[tid] = run;
  }
  __syncthreads();
  if (tid == 0){
    int b = 0, t1 = 0, t2 = 0;
    for (int e=0;e<NE;e++){
      int c = counts[e];
      int prows = ((c+127)>>7)<<7;        // 128-aligned padded rows (hbuf layout)
      bases[e] = b; b += prows;
      int nb1 = (prows + 255) >> 8;       // 256-row tiles (gemm1)
      for (int j=0;j<nb1 && t1<MAXT;j++){ tile_e[t1]=e; tile_by[t1]=j; t1++; }
      int nb2 = prows >> 7;               // 128-row tiles (gemm2)
      for (int j=0;j<nb2 && t2<MAXT2;j++){ tile2_e[t2]=e; tile2_by[t2]=j; t2++; }
    }
    bases[NE] = b; bases[NE+1] = b + TOKENS;
    for (int e=NE;e<NEX;e++){
      for (int j=0;j<16 && t1<MAXT;j++){ tile_e[t1]=e; tile_by[t1]=j; t1++; }
      for (int j=0;j<32 && t2<MAXT2;j++){ tile2_e[t2]=e; tile2_by[t2]=j; t2++; }
    }
    ntiles[0] = t1; ntiles[1] = t2;
  }
  __syncthreads();
  #pragma unroll
  for (int j=0;j<48;j++){
    const int t = t0 + (j/3), k = j - (j/3)*3;
    const int e = le[j];
    const int slot = lh[tid][e]++;
    const int idx = e*TOKENS + slot;
    tokidx[idx] = t;
    gatev[idx]  = tokp[t*3 + k];
    tokslot[t*3 + k] = idx;
  }
}

// ---------------- grouped GEMM 1: h = gelu(x @ W1 + b1) ----------------
// Tile 256x256, BK=32, NK=32. 512 thr / 8 waves (2M x 4N), per-wave 128x64.
// 3-deep LDS pipeline (3 x 32KB = 96KB): stage tile t+2 while computing t;
// boundary = vmcnt(4) [t+1 landed, t+2 in flight] + s_barrier. Swizzle:
// chunk ^= (row>>1)&3, applied on global source AND ds_read (rule #21).

__global__ __launch_bounds__(512,2) void gemm1_kernel(
    const ushort* __restrict__ xb, const ushort* __restrict__ rW1T,
    const ushort* __restrict__ sW1T, const float* __restrict__ rb1,
    const float* __restrict__ sb1, const int* __restrict__ counts,
    const int* __restrict__ bases, const int* __restrict__ tokidx,
    const int* __restrict__ tile_e, const int* __restrict__ tile_by,
    const int* __restrict__ ntiles, ushort* __restrict__ h)
{
  const int ty = blockIdx.y;
  if (ty >= ntiles[0]) return;
  const int e = tile_e[ty], by = tile_by[ty], bx = blockIdx.x;
  const int cnt = (e < NE) ? counts[e] : TOKENS;
  const int prows = (e < NE) ? (((cnt+127)>>7)<<7) : TOKENS;

  __shared__ __align__(16) char smem[98304];

  const int tid = threadIdx.x, wave = tid >> 6, lane = tid & 63;
  const int wr = wave >> 2, wc = wave & 3;
  const unsigned sc = (unsigned)(((tid & 3) ^ ((tid >> 3) & 3)) << 4);

  const char* Bpb = (e < NE) ? (const char*)rW1T + (size_t)e*DFR*2048
                             : (const char*)sW1T + (size_t)(e-NE)*DFR*2048;

  const char* aSrc[2];
  const char* bSrc[2];
  #pragma unroll
  for (int i=0;i<2;i++){
    const int rl = i*128 + (tid>>2);
    const int gr = by*256 + rl;
    int tok;
    if (e < NE){ const int cr = gr < cnt ? gr : cnt-1; tok = tokidx[e*TOKENS + cr]; }
    else       { tok = gr < TOKENS ? gr : TOKENS-1; }
    aSrc[i] = (const char*)xb + (size_t)tok*2048 + sc;
    bSrc[i] = Bpb + (size_t)(bx*256 + rl)*2048 + sc;
  }

  f32x4 acc[8][4];
  #pragma unroll
  for (int m=0;m<8;m++){
    #pragma unroll
    for (int n=0;n<4;n++){ acc[m][n] = (f32x4){0.f,0.f,0.f,0.f}; }
  }

#define G1_STAGE(BUF, T)                                                   \
  { char* bp = smem + (BUF)*32768;                                         \
    gload16(aSrc[0] + (T)*64, bp + tid*16);                                \
    gload16(aSrc[1] + (T)*64, bp + 8192 + tid*16);                         \
    gload16(bSrc[0] + (T)*64, bp + 16384 + tid*16);                        \
    gload16(bSrc[1] + (T)*64, bp + 24576 + tid*16); }

#define G1_COMPUTE(BUF)                                                    \
  { const char* bp = smem + (BUF)*32768;                                   \
    i32x4 bf[4];                                                           \
    _Pragma("unroll")                                                      \
    for (int n=0;n<4;n++){                                                 \
      const int row = wc*64 + n*16 + (lane&15);                            \
      bf[n] = *(const i32x4*)(bp + 16384 + row*64                          \
               + (((lane>>4) ^ ((row>>1)&3))<<4));                         \
    }                                                                      \
    _Pragma("unroll")                                                      \
    for (int q=0;q<2;q++){                                                 \
      i32x4 af[4];                                                         \
      _Pragma("unroll")                                                    \
      for (int m=0;m<4;m++){                                               \
        const int row = wr*128 + q*64 + m*16 + (lane&15);                  \
        af[m] = *(const i32x4*)(bp + row*64                                \
                 + (((lane>>4) ^ ((row>>1)&3))<<4));                       \
      }                                                                    \
      __builtin_amdgcn_s_setprio(1);                                       \
      _Pragma("unroll")                                                    \
      for (int m=0;m<4;m++){                                               \
        _Pragma("unroll")                                                  \
        for (int n=0;n<4;n++){ mfma_16x16x32_bf16(acc[q*4+m][n], af[m], bf[n]); } \
      }                                                                    \
      __builtin_amdgcn_s_setprio(0);                                       \
    } }

  const int NK = DM/32;   // 32
  G1_STAGE(0, 0);
  G1_STAGE(1, 1);
  asm volatile("s_waitcnt vmcnt(4)" ::: "memory");
  __builtin_amdgcn_s_barrier();
  int cb = 0;
  for (int t=0; t<NK; ++t){
    if (t+2 < NK){
      const int pb = (cb >= 1) ? cb-1 : cb+2;   // (cb+2)%3
      G1_STAGE(pb, t+2);
    }
    G1_COMPUTE(cb);
    if (t < NK-1){
      if (t+2 < NK) asm volatile("s_waitcnt vmcnt(4)" ::: "memory");
      else          asm volatile("s_waitcnt vmcnt(0)" ::: "memory");
      __builtin_amdgcn_s_barrier();
    }
    cb = (cb==2) ? 0 : cb+1;
  }

  const int hb = bases[e];
  const float* b1p = (e < NE) ? (rb1 + e*DFR + bx*256) : (sb1 + (e-NE)*DFR + bx*256);
  #pragma unroll
  for (int m=0;m<8;m++){
    const int rt = wr*128 + m*16 + (lane>>4)*4;
    #pragma unroll
    for (int i=0;i<4;i++){
      const int gr = by*256 + rt + i;
      if (gr < prows){
        #pragma unroll
        for (int n=0;n<4;n++){
          const int c = wc*64 + n*16 + (lane & 15);
          float v = acc[m][n][i] + b1p[c];
          h[(size_t)(hb + gr)*DFR + (size_t)bx*256 + c] = f2bf(gelu_exact(v));
        }
      }
    }
  }
#undef G1_STAGE
#undef G1_COMPUTE
}

// ---------------- grouped GEMM 2: rout[row] = h @ W2 + b2 (bf16, no gate) ----
// Tile 128x256, BK=32, NK=64. 512 thr / 8 waves (2M x 4N), per-wave 64x64.
// 3-deep LDS pipeline (3 x 24KB = 72KB -> 2 blocks/CU, 4 waves/SIMD).

__global__ __launch_bounds__(512,4) void gemm2_kernel(
    const ushort* __restrict__ hbuf, const ushort* __restrict__ rW2T,
    const ushort* __restrict__ sW2T, const float* __restrict__ rb2,
    const float* __restrict__ sb2, const int* __restrict__ counts,
    const int* __restrict__ bases,
    const int* __restrict__ tile2_e, const int* __restrict__ tile2_by,
    const int* __restrict__ ntiles, ushort* __restrict__ rout)
{
  const int ty = blockIdx.y;
  if (ty >= ntiles[1]) return;
  const int e = tile2_e[ty], by = tile2_by[ty], bx = blockIdx.x;
  const int cnt = (e < NE) ? counts[e] : TOKENS;
  const int prows = (e < NE) ? (((cnt+127)>>7)<<7) : TOKENS;
  const int hb = bases[e];

  __shared__ __align__(16) char smem[73728];

  const int tid = threadIdx.x, wave = tid >> 6, lane = tid & 63;
  const int wr = wave >> 2, wc = wave & 3;
  const unsigned sc = (unsigned)(((tid & 3) ^ ((tid >> 3) & 3)) << 4);

  const char* aSrc;
  {
    const int rl = tid>>2;
    int ar = by*128 + rl; if (ar >= prows) ar = prows-1;
    aSrc = (const char*)hbuf + (size_t)(hb + ar)*4096 + sc;
  }
  const char* bSrc[2];
  #pragma unroll
  for (int i=0;i<2;i++){
    const int rl = i*128 + (tid>>2);
    if (e < NE) bSrc[i] = (const char*)rW2T + ((size_t)e*DM + bx*256 + rl)*4096 + sc;
    else        bSrc[i] = (const char*)sW2T + (size_t)(bx*256 + rl)*8192 + (size_t)(e-NE)*4096 + sc;
  }

  f32x4 acc[4][4];
  #pragma unroll
  for (int m=0;m<4;m++){
    #pragma unroll
    for (int n=0;n<4;n++){ acc[m][n] = (f32x4){0.f,0.f,0.f,0.f}; }
  }

#define G2_STAGE(BUF, T)                                                   \
  { char* bp = smem + (BUF)*24576;                                         \
    gload16(aSrc + (T)*64, bp + tid*16);                                   \
    gload16(bSrc[0] + (T)*64, bp + 8192 + tid*16);                         \
    gload16(bSrc[1] + (T)*64, bp + 16384 + tid*16); }

#define G2_COMPUTE(BUF)                                                    \
  { const char* bp = smem + (BUF)*24576;                                   \
    i32x4 bf[4], af[4];                                                    \
    _Pragma("unroll")                                                      \
    for (int n=0;n<4;n++){                                                 \
      const int row = wc*64 + n*16 + (lane&15);                            \
      bf[n] = *(const i32x4*)(bp + 8192 + row*64                           \
               + (((lane>>4) ^ ((row>>1)&3))<<4));                         \
    }                                                                      \
    _Pragma("unroll")                                                      \
    for (int m=0;m<4;m++){                                                 \
      const int row = wr*64 + m*16 + (lane&15);                            \
      af[m] = *(const i32x4*)(bp + row*64                                  \
               + (((lane>>4) ^ ((row>>1)&3))<<4));                         \
    }                                                                      \
    __builtin_amdgcn_s_setprio(1);                                         \
    _Pragma("unroll")                                                      \
    for (int m=0;m<4;m++){                                                 \
      _Pragma("unroll")                                                    \
      for (int n=0;n<4;n++){ mfma_16x16x32_bf16(acc[m][n], af[m], bf[n]); }\
    }                                                                      \
    __builtin_amdgcn_s_setprio(0); }

  const int NK = DFR/32;  // 64
  G2_STAGE(0, 0);
  G2_STAGE(1, 1);
  asm volatile("s_waitcnt vmcnt(3)" ::: "memory");
  __builtin_amdgcn_s_barrier();
  int cb = 0;
  for (int t=0; t<NK; ++t){
    if (t+2 < NK){
      const int pb = (cb >= 1) ? cb-1 : cb+2;   // (cb+2)%3
      G2_STAGE(pb, t+2);
    }
    G2_COMPUTE(cb);
    if (t < NK-1){
      if (t+2 < NK) asm volatile("s_waitcnt vmcnt(3)" ::: "memory");
      else          asm volatile("s_waitcnt vmcnt(0)" ::: "memory");
      __builtin_amdgcn_s_barrier();
    }
    cb = (cb==2) ? 0 : cb+1;
  }

  #pragma unroll
  for (int m=0;m<4;m++){
    const int rt = wr*64 + m*16 + (lane>>4)*4;
    #pragma unroll
    for (int i=0;i<4;i++){
      const int gr = by*128 + rt + i;
      if (gr < prows){
        #pragma unroll
        for (int n=0;n<4;n++){
          const int c  = wc*64 + n*16 + (lane & 15);
          const int cg = bx*256 + c;
          const float bias = (e < NE) ? rb2[e*DM + cg] : ((e == NE) ? sb2[cg] : 0.f);
          rout[(size_t)(hb + gr)*DM + cg] = f2bf(acc[m][n][i] + bias);
        }
      }
    }
  }
#undef G2_STAGE
#undef G2_COMPUTE
}

// ---------------- combine: out = x + sh0 + sh1 + sum_k gate_k * rout ----------

__global__ void combine_kernel(const float* __restrict__ x, const ushort* __restrict__ rout,
                               const int* __restrict__ bases, const int* __restrict__ tokslot,
                               const float* __restrict__ gatev, float* __restrict__ out)
{
  const int wave = threadIdx.x >> 6, lane = threadIdx.x & 63;
  const int token = blockIdx.x*4 + wave;
  const int d0 = lane*16;

  float acc[16];
  #pragma unroll
  for (int j=0;j<4;j++){
    float4 v = reinterpret_cast<const float4*>(x + (size_t)token*DM + d0)[j];
    acc[j*4+0]=v.x; acc[j*4+1]=v.y; acc[j*4+2]=v.z; acc[j*4+3]=v.w;
  }

  int   rows[5];
  float gs[5];
  rows[0] = bases[NE]   + token; gs[0] = 1.f;
  rows[1] = bases[NE+1] + token; gs[1] = 1.f;
  #pragma unroll
  for (int k=0;k<3;k++){
    const int idx = tokslot[token*3 + k];
    const int e = idx >> 12, s = idx & (TOKENS-1);
    rows[2+k] = bases[e] + s;
    gs[2+k] = gatev[idx];
  }

  #pragma unroll
  for (int q=0;q<5;q++){
    const float g = gs[q];
    const ushort* rp = rout + (size_t)rows[q]*DM + d0;
    #pragma unroll
    for (int hh=0;hh<2;hh++){
      i32x4 v = *reinterpret_cast<const i32x4*>(rp + hh*8);
      #pragma unroll
      for (int j=0;j<4;j++){
        const unsigned u = (unsigned)v[j];
        acc[hh*8 + j*2 + 0] += g * __uint_as_float(u << 16);
        acc[hh*8 + j*2 + 1] += g * __uint_as_float(u & 0xFFFF0000u);
      }
    }
  }

  #pragma unroll
  for (int j=0;j<4;j++){
    float4 v; v.x=acc[j*4+0]; v.y=acc[j*4+1]; v.z=acc[j*4+2]; v.w=acc[j*4+3];
    reinterpret_cast<float4*>(out + (size_t)token*DM + d0)[j] = v;
  }
}

// ---------------- launcher ----------------

extern "C" void kernel_launch(void* const* d_in, const int* in_sizes, int n_in,
                              void* d_out, int out_size, void* d_ws, size_t ws_size,
                              hipStream_t stream)
{
  (void)in_sizes; (void)n_in; (void)out_size; (void)ws_size;
  const float* x   = (const float*)d_in[0];
  const float* sW1 = (const float*)d_in[1];
  const float* sb1 = (const float*)d_in[2];
  const float* sW2 = (const float*)d_in[3];
  const float* sb2 = (const float*)d_in[4];
  const float* rW1 = (const float*)d_in[5];
  const float* rb1 = (const float*)d_in[6];
  const float* rW2 = (const float*)d_in[7];
  const float* rb2 = (const float*)d_in[8];
  const float* gW  = (const float*)d_in[9];
  const float* gb  = (const float*)d_in[10];
  float* out = (float*)d_out;

  char* ws = (char*)d_ws;
  ushort* xb   = (ushort*)(ws + 0);          //  8,388,608  x bf16 [4096][1024]
  ushort* sW1T = (ushort*)(ws + 8388608);    //  8,388,608  [4096][1024]
  ushort* sW2T = (ushort*)(ws + 16777216);   //  8,388,608  [1024][4096]
  ushort* rW1T = (ushort*)(ws + 25165824);   // 62,914,560  [15][2048][1024]
  ushort* rW2T = (ushort*)(ws + 88080384);   // 62,914,560  [15][1024][2048]
  ushort* hbuf = (ushort*)(ws + 150994944);  // 92,274,688  [22528][2048]
  // rout ALIASES rW1T's region: rW1T is dead after gemm1, rout written by gemm2.
  ushort* rout = (ushort*)(ws + 25165824);   // 46,137,344  [22528][1024]
  int*   counts  = (int*)(ws + 243269632);
  int*   bases   = (int*)(ws + 243269760);
  int*   tokidx  = (int*)(ws + 243270144);   // 15*4096 ints
  float* gatev   = (float*)(ws + 243515904); // 15*4096 floats
  int*   tokslot = (int*)(ws + 243761664);   // 4096*3 ints
  int*   tokexp  = (int*)(ws + 243810816);   // 4096*3 ints
  float* tokp    = (float*)(ws + 243859968); // 4096*3 floats
  int*   tile_e  = (int*)(ws + 243909120);   // MAXT ints
  int*   tile_by = (int*)(ws + 243910144);
  int*   ntiles  = (int*)(ws + 243911168);   // 2 ints
  int*   tile2_e = (int*)(ws + 243912192);   // MAXT2 ints
  int*   tile2_by= (int*)(ws + 243913216);
  // total ~244 MB of workspace

  cast_x_kernel<<<dim3(TOKENS*DM/4/256), dim3(256), 0, stream>>>(x, xb, TOKENS*DM/4);
  tcast_kernel<<<dim3(DFF/32, DM/32, 1),  dim3(32,8), 0, stream>>>(sW1, sW1T, DM, DFF);
  tcast_kernel<<<dim3(DM/32, DFF/32, 1),  dim3(32,8), 0, stream>>>(sW2, sW2T, DFF, DM);
  tcast_kernel<<<dim3(DFR/32, DM/32, NE), dim3(32,8), 0, stream>>>(rW1, rW1T, DM, DFR);
  tcast_kernel<<<dim3(DM/32, DFR/32, NE), dim3(32,8), 0, stream>>>(rW2, rW2T, DFR, DM);

  gate_kernel<<<dim3(TOKENS/4), dim3(256), 0, stream>>>(x, gW, gb, tokexp, tokp);
  assign_kernel<<<dim3(1), dim3(256), 0, stream>>>(tokexp, tokp, counts, bases,
                                                   tokidx, gatev, tokslot,
                                                   tile_e, tile_by, tile2_e, tile2_by, ntiles);

  gemm1_kernel<<<dim3(8,MAXT), dim3(512), 0, stream>>>(
      xb, rW1T, sW1T, rb1, sb1, counts, bases, tokidx, tile_e, tile_by, ntiles, hbuf);
  gemm2_kernel<<<dim3(4,MAXT2), dim3(512), 0, stream>>>(
      hbuf, rW2T, sW2T, rb2, sb2, counts, bases, tile2_e, tile2_by, ntiles, rout);
  combine_kernel<<<dim3(TOKENS/4), dim3(256), 0, stream>>>(
      x, rout, bases, tokslot, gatev, out);
}

// Round 9
// 430.263 us; speedup vs baseline: 1.1434x; 1.0479x over previous
//
#include <hip/hip_runtime.h>
#include <hip/hip_bf16.h>
#include <cstdint>
#include <cstddef>

#define TOKENS 4096
#define DM     1024
#define DFF    4096
#define NE     15     // router experts
#define DFR    2048   // router expert hidden (and shared half)
#define NEX    17     // 15 router + 2 shared halves
#define MAXT   176    // 128-row M-tiles: router <=111 + 64 shared

typedef float f32x4 __attribute__((ext_vector_type(4)));
typedef int   i32x4 __attribute__((ext_vector_type(4)));
typedef __attribute__((ext_vector_type(8))) short short8;   // 8 bf16 (4 VGPRs)

__device__ __forceinline__ void mfma_bf16(f32x4& d, short8 a, short8 b){
  d = __builtin_amdgcn_mfma_f32_16x16x32_bf16(a, b, d, 0, 0, 0);
}

__device__ __forceinline__ void gload16(const void* g, void* l){
  __builtin_amdgcn_global_load_lds(
      (const __attribute__((address_space(1))) uint32_t*)g,
      (__attribute__((address_space(3))) uint32_t*)l, 16, 0, 0);
}

__device__ __forceinline__ unsigned short f2bf(float f){
  unsigned u = __float_as_uint(f);
  u += 0x7FFFu + ((u >> 16) & 1u);      // round-to-nearest-even
  return (unsigned short)(u >> 16);
}

__device__ __forceinline__ float gelu_exact(float v){
  return 0.5f * v * (1.0f + erff(v * 0.70710678118654752440f));
}

// ---------------- prep kernels ----------------

// src [batch][R][C] f32 -> dst [batch][C][R] bf16
__global__ void tcast_kernel(const float* __restrict__ src, ushort* __restrict__ dst, int R, int C){
  __shared__ float tile[32][33];
  const size_t bo = (size_t)blockIdx.z * R * C;
  const int c0 = blockIdx.x*32, r0 = blockIdx.y*32;
  const int tx = threadIdx.x, ty = threadIdx.y;
  #pragma unroll
  for (int i=0;i<4;i++){
    int r = ty + i*8;
    tile[r][tx] = src[bo + (size_t)(r0+r)*C + c0 + tx];
  }
  __syncthreads();
  #pragma unroll
  for (int i=0;i<4;i++){
    int r = ty + i*8;
    dst[bo + (size_t)(c0+r)*R + r0 + tx] = f2bf(tile[tx][r]);
  }
}

// ---------------- gating (fused x->bf16 cast + per-token top-3, NO atomics) ----

__global__ void gate_kernel(const float* __restrict__ x, const float* __restrict__ gW,
                            const float* __restrict__ gb, ushort* __restrict__ xb,
                            int* __restrict__ tokexp, float* __restrict__ tokp){
  const int wave = threadIdx.x >> 6, lane = threadIdx.x & 63;
  const int token = blockIdx.x*4 + wave;
  const float* xr = x + (size_t)token * DM;
  float a[NE];
  #pragma unroll
  for (int e=0;e<NE;e++) a[e] = 0.f;
  const int d0 = lane * 16;
  float xv[16];
  #pragma unroll
  for (int j=0;j<4;j++){
    float4 v = reinterpret_cast<const float4*>(xr + d0)[j];
    xv[j*4+0]=v.x; xv[j*4+1]=v.y; xv[j*4+2]=v.z; xv[j*4+3]=v.w;
  }
  // fused bf16 cast of x (replaces cast_x_kernel)
  {
    ushort o[16];
    #pragma unroll
    for (int j=0;j<16;j++) o[j] = f2bf(xv[j]);
    ushort* dst = xb + (size_t)token*DM + d0;
    *reinterpret_cast<i32x4*>(dst)     = *reinterpret_cast<const i32x4*>(&o[0]);
    *reinterpret_cast<i32x4*>(dst + 8) = *reinterpret_cast<const i32x4*>(&o[8]);
  }
  for (int j=0;j<16;j++){
    const float* gr = gW + (size_t)(d0 + j) * NE;
    #pragma unroll
    for (int e=0;e<NE;e++) a[e] += xv[j]*gr[e];
  }
  #pragma unroll
  for (int e=0;e<NE;e++){
    for (int off=32; off; off>>=1) a[e] += __shfl_xor(a[e], off, 64);
  }
  if (lane == 0){
    float l[NE], p[NE];
    float m = -1e30f;
    for (int e=0;e<NE;e++){ l[e] = a[e] + gb[e]; m = fmaxf(m, l[e]); }
    float s = 0.f;
    for (int e=0;e<NE;e++){ p[e] = expf(l[e]-m); s += p[e]; }
    float inv = 1.f/s;
    unsigned used = 0;
    for (int k=0;k<3;k++){
      int best = -1; float bv = -1e30f;
      for (int e=0;e<NE;e++) if (!((used>>e)&1u) && l[e] > bv){ bv = l[e]; best = e; }
      used |= 1u<<best;
      tokexp[token*3 + k] = best;
      tokp[token*3 + k]   = p[best]*inv;
    }
  }
}

// ---------------- gating (phase B: deterministic slot assignment, 1 block) ----
// Also builds the dense 128-row M-tile table (contiguous active prefix).

__global__ void assign_kernel(const int* __restrict__ tokexp, const float* __restrict__ tokp,
                              int* __restrict__ counts, int* __restrict__ bases,
                              int* __restrict__ tokidx, float* __restrict__ gatev,
                              int* __restrict__ tokslot,
                              int* __restrict__ tile_e, int* __restrict__ tile_by,
                              int* __restrict__ ntiles){
  __shared__ int lh[256][NE];      // per-thread-chunk histogram
  const int tid = threadIdx.x;
  const int t0 = tid * 16;

  int le[48];                      // this chunk's expert picks (16 tokens x 3)
  #pragma unroll
  for (int e=0;e<NE;e++) lh[tid][e] = 0;
  #pragma unroll
  for (int j=0;j<48;j++){
    int e = tokexp[t0*3 + j];
    le[j] = e;
    lh[tid][e]++;
  }
  __syncthreads();
  if (tid < NE){
    int run = 0;
    for (int i=0;i<256;i++){
      int v = lh[i][tid];
      lh[i][tid] = run;
      run += v;
    }
    counts[tid] = run;
  }
  __syncthreads();
  if (tid == 0){
    int b = 0, t = 0;
    for (int e=0;e<NE;e++){
      int c = counts[e];
      int prows = ((c+127)>>7)<<7;        // 128-aligned padded rows
      bases[e] = b; b += prows;
      int nb = prows >> 7;
      for (int j=0;j<nb && t<MAXT;j++){ tile_e[t]=e; tile_by[t]=j; t++; }
    }
    bases[NE] = b; bases[NE+1] = b + TOKENS;
    for (int e=NE;e<NEX;e++){
      for (int j=0;j<32 && t<MAXT;j++){ tile_e[t]=e; tile_by[t]=j; t++; }
    }
    ntiles[0] = t;
  }
  __syncthreads();
  #pragma unroll
  for (int j=0;j<48;j++){
    const int t = t0 + (j/3), k = j - (j/3)*3;
    const int e = le[j];
    const int slot = lh[tid][e]++;
    const int idx = e*TOKENS + slot;
    tokidx[idx] = t;
    gatev[idx]  = tokp[t*3 + k];
    tokslot[t*3 + k] = idx;
  }
}

// ---------------- grouped GEMM 1: h = gelu(x @ W1 + b1) ----------------
// grid (16, MAXT), block 256. Tile 128x128, BK=64. R6-proven structure;
// MFMA via builtin so the compiler can interleave ds_read/MFMA (m97 behavior).

__global__ __launch_bounds__(256,3) void gemm1_kernel(
    const ushort* __restrict__ xb, const ushort* __restrict__ rW1T,
    const ushort* __restrict__ sW1T, const float* __restrict__ rb1,
    const float* __restrict__ sb1, const int* __restrict__ counts,
    const int* __restrict__ bases, const int* __restrict__ tokidx,
    const int* __restrict__ tile_e, const int* __restrict__ tile_by,
    const int* __restrict__ ntiles, ushort* __restrict__ h)
{
  const int ty = blockIdx.y;
  if (ty >= ntiles[0]) return;
  const int e = tile_e[ty], by = tile_by[ty], bx = blockIdx.x;
  const int cnt = (e < NE) ? counts[e] : TOKENS;

  __shared__ __align__(16) ushort lA[128*64];
  __shared__ __align__(16) ushort lB[128*64];

  const int tid = threadIdx.x, wave = tid >> 6, lane = tid & 63;
  const int wr = wave >> 1, wc = wave & 1;

  const ushort* Bp = (e < NE) ? (rW1T + ((size_t)e*DFR + (size_t)bx*128)*DM)
                              : (sW1T + ((size_t)(e-NE)*DFR + (size_t)bx*128)*DM);

  const ushort* srcA[4];
  const ushort* srcB[4];
  unsigned ldso[4];
  #pragma unroll
  for (int i=0;i<4;i++){
    const int rt = i*32 + wave*8 + (lane>>3);
    const int gr = by*128 + rt;
    const int tok = (e < NE) ? tokidx[e*TOKENS + (gr < cnt ? gr : cnt-1)] : gr;
    srcA[i] = xb + (size_t)tok*DM + (lane&7)*8;
    srcB[i] = Bp + (size_t)rt*DM + (lane&7)*8;
    ldso[i] = (unsigned)(i*4096 + wave*1024 + lane*16);
  }

  f32x4 acc[4][4];
  #pragma unroll
  for (int m=0;m<4;m++){
    #pragma unroll
    for (int n=0;n<4;n++){ acc[m][n] = (f32x4){0.f,0.f,0.f,0.f}; }
  }

  for (int k0=0; k0<DM; k0+=64){
    __syncthreads();
    #pragma unroll
    for (int i=0;i<4;i++){ gload16(srcA[i]+k0, (char*)lA + ldso[i]); }
    #pragma unroll
    for (int i=0;i<4;i++){ gload16(srcB[i]+k0, (char*)lB + ldso[i]); }
    __syncthreads();
    #pragma unroll
    for (int kk=0; kk<2; kk++){
      short8 af[4], bfr[4];
      #pragma unroll
      for (int m=0;m<4;m++){
        af[m] = *(const short8*)((const char*)lA + ((wr*64 + m*16 + (lane&15))*128 + kk*64 + (lane>>4)*16));
      }
      #pragma unroll
      for (int n=0;n<4;n++){
        bfr[n] = *(const short8*)((const char*)lB + ((wc*64 + n*16 + (lane&15))*128 + kk*64 + (lane>>4)*16));
      }
      #pragma unroll
      for (int m=0;m<4;m++){
        #pragma unroll
        for (int n=0;n<4;n++){ mfma_bf16(acc[m][n], af[m], bfr[n]); }
      }
    }
  }

  const int hb = bases[e];
  const float* b1p = (e < NE) ? (rb1 + e*DFR + bx*128) : (sb1 + (e-NE)*DFR + bx*128);
  #pragma unroll
  for (int m=0;m<4;m++){
    #pragma unroll
    for (int n=0;n<4;n++){
      const int c = wc*64 + n*16 + (lane & 15);
      const float bias = b1p[c];
      #pragma unroll
      for (int i=0;i<4;i++){
        const int r = wr*64 + m*16 + (lane>>4)*4 + i;
        float v = acc[m][n][i] + bias;
        h[(size_t)(hb + by*128 + r)*DFR + (size_t)bx*128 + c] = f2bf(gelu_exact(v));
      }
    }
  }
}

// ---------------- grouped GEMM 2: rout[row] = h @ W2 + b2 (bf16, no gate) ----
// grid (8, MAXT), block 256.

__global__ __launch_bounds__(256,3) void gemm2_kernel(
    const ushort* __restrict__ hbuf, const ushort* __restrict__ rW2T,
    const ushort* __restrict__ sW2T, const float* __restrict__ rb2,
    const float* __restrict__ sb2, const int* __restrict__ counts,
    const int* __restrict__ bases,
    const int* __restrict__ tile_e, const int* __restrict__ tile_by,
    const int* __restrict__ ntiles, ushort* __restrict__ rout)
{
  const int ty = blockIdx.y;
  if (ty >= ntiles[0]) return;
  const int e = tile_e[ty], by = tile_by[ty], bx = blockIdx.x;

  __shared__ __align__(16) ushort lA[128*64];
  __shared__ __align__(16) ushort lB[128*64];

  const int tid = threadIdx.x, wave = tid >> 6, lane = tid & 63;
  const int wr = wave >> 1, wc = wave & 1;

  const int hb = bases[e];
  const ushort* Ab = hbuf + (size_t)(hb + by*128)*DFR;
  const ushort* Bp; size_t ldb;
  if (e < NE){ Bp = rW2T + ((size_t)e*DM + (size_t)bx*128)*DFR; ldb = DFR; }
  else       { Bp = sW2T + (size_t)(bx*128)*DFF + (size_t)(e-NE)*DFR; ldb = DFF; }

  const ushort* srcA[4];
  const ushort* srcB[4];
  unsigned ldso[4];
  #pragma unroll
  for (int i=0;i<4;i++){
    const int rt = i*32 + wave*8 + (lane>>3);
    srcA[i] = Ab + (size_t)rt*DFR + (lane&7)*8;
    srcB[i] = Bp + (size_t)rt*ldb + (lane&7)*8;
    ldso[i] = (unsigned)(i*4096 + wave*1024 + lane*16);
  }

  f32x4 acc[4][4];
  #pragma unroll
  for (int m=0;m<4;m++){
    #pragma unroll
    for (int n=0;n<4;n++){ acc[m][n] = (f32x4){0.f,0.f,0.f,0.f}; }
  }

  for (int k0=0; k0<DFR; k0+=64){
    __syncthreads();
    #pragma unroll
    for (int i=0;i<4;i++){ gload16(srcA[i]+k0, (char*)lA + ldso[i]); }
    #pragma unroll
    for (int i=0;i<4;i++){ gload16(srcB[i]+k0, (char*)lB + ldso[i]); }
    __syncthreads();
    #pragma unroll
    for (int kk=0; kk<2; kk++){
      short8 af[4], bfr[4];
      #pragma unroll
      for (int m=0;m<4;m++){
        af[m] = *(const short8*)((const char*)lA + ((wr*64 + m*16 + (lane&15))*128 + kk*64 + (lane>>4)*16));
      }
      #pragma unroll
      for (int n=0;n<4;n++){
        bfr[n] = *(const short8*)((const char*)lB + ((wc*64 + n*16 + (lane&15))*128 + kk*64 + (lane>>4)*16));
      }
      #pragma unroll
      for (int m=0;m<4;m++){
        #pragma unroll
        for (int n=0;n<4;n++){ mfma_bf16(acc[m][n], af[m], bfr[n]); }
      }
    }
  }

  #pragma unroll
  for (int m=0;m<4;m++){
    #pragma unroll
    for (int n=0;n<4;n++){
      const int c  = wc*64 + n*16 + (lane & 15);
      const int cg = bx*128 + c;
      const float bias = (e < NE) ? rb2[e*DM + cg] : ((e == NE) ? sb2[cg] : 0.f);
      #pragma unroll
      for (int i=0;i<4;i++){
        const int r = wr*64 + m*16 + (lane>>4)*4 + i;
        rout[(size_t)(hb + by*128 + r)*DM + cg] = f2bf(acc[m][n][i] + bias);
      }
    }
  }
}

// ---------------- combine: out = x + sh0 + sh1 + sum_k gate_k * rout ----------

__global__ void combine_kernel(const float* __restrict__ x, const ushort* __restrict__ rout,
                               const int* __restrict__ bases, const int* __restrict__ tokslot,
                               const float* __restrict__ gatev, float* __restrict__ out)
{
  const int wave = threadIdx.x >> 6, lane = threadIdx.x & 63;
  const int token = blockIdx.x*4 + wave;
  const int d0 = lane*16;

  float acc[16];
  #pragma unroll
  for (int j=0;j<4;j++){
    float4 v = reinterpret_cast<const float4*>(x + (size_t)token*DM + d0)[j];
    acc[j*4+0]=v.x; acc[j*4+1]=v.y; acc[j*4+2]=v.z; acc[j*4+3]=v.w;
  }

  int   rows[5];
  float gs[5];
  rows[0] = bases[NE]   + token; gs[0] = 1.f;
  rows[1] = bases[NE+1] + token; gs[1] = 1.f;
  #pragma unroll
  for (int k=0;k<3;k++){
    const int idx = tokslot[token*3 + k];
    const int e = idx >> 12, s = idx & (TOKENS-1);
    rows[2+k] = bases[e] + s;
    gs[2+k] = gatev[idx];
  }

  #pragma unroll
  for (int q=0;q<5;q++){
    const float g = gs[q];
    const ushort* rp = rout + (size_t)rows[q]*DM + d0;
    #pragma unroll
    for (int hh=0;hh<2;hh++){
      i32x4 v = *reinterpret_cast<const i32x4*>(rp + hh*8);
      #pragma unroll
      for (int j=0;j<4;j++){
        const unsigned u = (unsigned)v[j];
        acc[hh*8 + j*2 + 0] += g * __uint_as_float(u << 16);
        acc[hh*8 + j*2 + 1] += g * __uint_as_float(u & 0xFFFF0000u);
      }
    }
  }

  #pragma unroll
  for (int j=0;j<4;j++){
    float4 v; v.x=acc[j*4+0]; v.y=acc[j*4+1]; v.z=acc[j*4+2]; v.w=acc[j*4+3];
    reinterpret_cast<float4*>(out + (size_t)token*DM + d0)[j] = v;
  }
}

// ---------------- launcher ----------------

extern "C" void kernel_launch(void* const* d_in, const int* in_sizes, int n_in,
                              void* d_out, int out_size, void* d_ws, size_t ws_size,
                              hipStream_t stream)
{
  (void)in_sizes; (void)n_in; (void)out_size; (void)ws_size;
  const float* x   = (const float*)d_in[0];
  const float* sW1 = (const float*)d_in[1];
  const float* sb1 = (const float*)d_in[2];
  const float* sW2 = (const float*)d_in[3];
  const float* sb2 = (const float*)d_in[4];
  const float* rW1 = (const float*)d_in[5];
  const float* rb1 = (const float*)d_in[6];
  const float* rW2 = (const float*)d_in[7];
  const float* rb2 = (const float*)d_in[8];
  const float* gW  = (const float*)d_in[9];
  const float* gb  = (const float*)d_in[10];
  float* out = (float*)d_out;

  char* ws = (char*)d_ws;
  ushort* xb   = (ushort*)(ws + 0);          //  8,388,608  x bf16 [4096][1024]
  ushort* sW1T = (ushort*)(ws + 8388608);    //  8,388,608  [4096][1024]
  ushort* sW2T = (ushort*)(ws + 16777216);   //  8,388,608  [1024][4096]
  ushort* rW1T = (ushort*)(ws + 25165824);   // 62,914,560  [15][2048][1024]
  ushort* rW2T = (ushort*)(ws + 88080384);   // 62,914,560  [15][1024][2048]
  ushort* hbuf = (ushort*)(ws + 150994944);  // 92,274,688  [22528][2048]
  // rout ALIASES rW1T's region: rW1T is dead after gemm1, rout written by gemm2.
  ushort* rout = (ushort*)(ws + 25165824);   // 46,137,344  [22528][1024]
  int*   counts  = (int*)(ws + 243269632);
  int*   bases   = (int*)(ws + 243269760);
  int*   tokidx  = (int*)(ws + 243270144);   // 15*4096 ints
  float* gatev   = (float*)(ws + 243515904); // 15*4096 floats
  int*   tokslot = (int*)(ws + 243761664);   // 4096*3 ints
  int*   tokexp  = (int*)(ws + 243810816);   // 4096*3 ints
  float* tokp    = (float*)(ws + 243859968); // 4096*3 floats
  int*   tile_e  = (int*)(ws + 243909120);   // MAXT ints
  int*   tile_by = (int*)(ws + 243910144);
  int*   ntiles  = (int*)(ws + 243911168);
  // total ~244 MB of workspace

  tcast_kernel<<<dim3(DFF/32, DM/32, 1),  dim3(32,8), 0, stream>>>(sW1, sW1T, DM, DFF);
  tcast_kernel<<<dim3(DM/32, DFF/32, 1),  dim3(32,8), 0, stream>>>(sW2, sW2T, DFF, DM);
  tcast_kernel<<<dim3(DFR/32, DM/32, NE), dim3(32,8), 0, stream>>>(rW1, rW1T, DM, DFR);
  tcast_kernel<<<dim3(DM/32, DFR/32, NE), dim3(32,8), 0, stream>>>(rW2, rW2T, DFR, DM);

  gate_kernel<<<dim3(TOKENS/4), dim3(256), 0, stream>>>(x, gW, gb, xb, tokexp, tokp);
  assign_kernel<<<dim3(1), dim3(256), 0, stream>>>(tokexp, tokp, counts, bases,
                                                   tokidx, gatev, tokslot,
                                                   tile_e, tile_by, ntiles);

  gemm1_kernel<<<dim3(16,MAXT), dim3(256), 0, stream>>>(
      xb, rW1T, sW1T, rb1, sb1, counts, bases, tokidx, tile_e, tile_by, ntiles, hbuf);
  gemm2_kernel<<<dim3(8,MAXT), dim3(256), 0, stream>>>(
      hbuf, rW2T, sW2T, rb2, sb2, counts, bases, tile_e, tile_by, ntiles, rout);
  combine_kernel<<<dim3(TOKENS/4), dim3(256), 0, stream>>>(
      x, rout, bases, tokslot, gatev, out);
}

// Round 10
// 409.118 us; speedup vs baseline: 1.2024x; 1.0517x over previous
//
#include <hip/hip_runtime.h>
#include <hip/hip_bf16.h>
#include <cstdint>
#include <cstddef>

#define TOKENS 4096
#define DM     1024
#define DFF    4096
#define NE     15     // router experts
#define DFR    2048   // router expert hidden (and shared half)
#define NEX    17     // 15 router + 2 shared halves
#define MAXT   176    // 128-row M-tiles: router <=111 + 64 shared

typedef float f32x4 __attribute__((ext_vector_type(4)));
typedef int   i32x4 __attribute__((ext_vector_type(4)));

__device__ __forceinline__ void mfma_16x16x32_bf16(f32x4& d, i32x4 a, i32x4 b){
  asm("v_mfma_f32_16x16x32_bf16 %0, %1, %2, %0" : "+v"(d) : "v"(a), "v"(b));
}

__device__ __forceinline__ void gload16(const void* g, void* l){
  __builtin_amdgcn_global_load_lds(
      (const __attribute__((address_space(1))) uint32_t*)g,
      (__attribute__((address_space(3))) uint32_t*)l, 16, 0, 0);
}

__device__ __forceinline__ unsigned short f2bf(float f){
  unsigned u = __float_as_uint(f);
  u += 0x7FFFu + ((u >> 16) & 1u);      // round-to-nearest-even
  return (unsigned short)(u >> 16);
}

// tanh-form GELU: x * sigmoid(1.5957692(x + 0.044715 x^3)).
// |diff vs erf-form| <= ~5e-3 per element; through W2 adds <~1e-3 to output.
// Replaces erff (~20+ instr) with ~8 instrs -> cuts gemm1 epilogue VALU tax.
__device__ __forceinline__ float gelu_fast(float v){
  float u = 1.5957691216057308f * (v + 0.044715f * v * v * v);
  float e = __expf(-u);
  return v / (1.0f + e);
}

// ---------------- prep kernels ----------------

// src [batch][R][C] f32 -> dst [batch][C][R] bf16
__global__ void tcast_kernel(const float* __restrict__ src, ushort* __restrict__ dst, int R, int C){
  __shared__ float tile[32][33];
  const size_t bo = (size_t)blockIdx.z * R * C;
  const int c0 = blockIdx.x*32, r0 = blockIdx.y*32;
  const int tx = threadIdx.x, ty = threadIdx.y;
  #pragma unroll
  for (int i=0;i<4;i++){
    int r = ty + i*8;
    tile[r][tx] = src[bo + (size_t)(r0+r)*C + c0 + tx];
  }
  __syncthreads();
  #pragma unroll
  for (int i=0;i<4;i++){
    int r = ty + i*8;
    dst[bo + (size_t)(c0+r)*R + r0 + tx] = f2bf(tile[tx][r]);
  }
}

// ---------------- gating (fused x->bf16 cast + per-token top-3, NO atomics) ----

__global__ void gate_kernel(const float* __restrict__ x, const float* __restrict__ gW,
                            const float* __restrict__ gb, ushort* __restrict__ xb,
                            int* __restrict__ tokexp, float* __restrict__ tokp){
  const int wave = threadIdx.x >> 6, lane = threadIdx.x & 63;
  const int token = blockIdx.x*4 + wave;
  const float* xr = x + (size_t)token * DM;
  float a[NE];
  #pragma unroll
  for (int e=0;e<NE;e++) a[e] = 0.f;
  const int d0 = lane * 16;
  float xv[16];
  #pragma unroll
  for (int j=0;j<4;j++){
    float4 v = reinterpret_cast<const float4*>(xr + d0)[j];
    xv[j*4+0]=v.x; xv[j*4+1]=v.y; xv[j*4+2]=v.z; xv[j*4+3]=v.w;
  }
  // fused bf16 cast of x (replaces cast_x_kernel)
  {
    ushort o[16];
    #pragma unroll
    for (int j=0;j<16;j++) o[j] = f2bf(xv[j]);
    ushort* dst = xb + (size_t)token*DM + d0;
    *reinterpret_cast<i32x4*>(dst)     = *reinterpret_cast<const i32x4*>(&o[0]);
    *reinterpret_cast<i32x4*>(dst + 8) = *reinterpret_cast<const i32x4*>(&o[8]);
  }
  for (int j=0;j<16;j++){
    const float* gr = gW + (size_t)(d0 + j) * NE;
    #pragma unroll
    for (int e=0;e<NE;e++) a[e] += xv[j]*gr[e];
  }
  #pragma unroll
  for (int e=0;e<NE;e++){
    for (int off=32; off; off>>=1) a[e] += __shfl_xor(a[e], off, 64);
  }
  if (lane == 0){
    float l[NE], p[NE];
    float m = -1e30f;
    for (int e=0;e<NE;e++){ l[e] = a[e] + gb[e]; m = fmaxf(m, l[e]); }
    float s = 0.f;
    for (int e=0;e<NE;e++){ p[e] = expf(l[e]-m); s += p[e]; }
    float inv = 1.f/s;
    unsigned used = 0;
    for (int k=0;k<3;k++){
      int best = -1; float bv = -1e30f;
      for (int e=0;e<NE;e++) if (!((used>>e)&1u) && l[e] > bv){ bv = l[e]; best = e; }
      used |= 1u<<best;
      tokexp[token*3 + k] = best;
      tokp[token*3 + k]   = p[best]*inv;
    }
  }
}

// ---------------- gating (phase B: deterministic slot assignment, 1 block) ----
// Also builds the dense 128-row M-tile table (contiguous active prefix).

__global__ void assign_kernel(const int* __restrict__ tokexp, const float* __restrict__ tokp,
                              int* __restrict__ counts, int* __restrict__ bases,
                              int* __restrict__ tokidx, float* __restrict__ gatev,
                              int* __restrict__ tokslot,
                              int* __restrict__ tile_e, int* __restrict__ tile_by,
                              int* __restrict__ ntiles){
  __shared__ int lh[256][NE];      // per-thread-chunk histogram
  const int tid = threadIdx.x;
  const int t0 = tid * 16;

  int le[48];                      // this chunk's expert picks (16 tokens x 3)
  #pragma unroll
  for (int e=0;e<NE;e++) lh[tid][e] = 0;
  #pragma unroll
  for (int j=0;j<48;j++){
    int e = tokexp[t0*3 + j];
    le[j] = e;
    lh[tid][e]++;
  }
  __syncthreads();
  if (tid < NE){
    int run = 0;
    for (int i=0;i<256;i++){
      int v = lh[i][tid];
      lh[i][tid] = run;
      run += v;
    }
    counts[tid] = run;
  }
  __syncthreads();
  if (tid == 0){
    int b = 0, t = 0;
    for (int e=0;e<NE;e++){
      int c = counts[e];
      int prows = ((c+127)>>7)<<7;        // 128-aligned padded rows
      bases[e] = b; b += prows;
      int nb = prows >> 7;
      for (int j=0;j<nb && t<MAXT;j++){ tile_e[t]=e; tile_by[t]=j; t++; }
    }
    bases[NE] = b; bases[NE+1] = b + TOKENS;
    for (int e=NE;e<NEX;e++){
      for (int j=0;j<32 && t<MAXT;j++){ tile_e[t]=e; tile_by[t]=j; t++; }
    }
    ntiles[0] = t;
  }
  __syncthreads();
  #pragma unroll
  for (int j=0;j<48;j++){
    const int t = t0 + (j/3), k = j - (j/3)*3;
    const int e = le[j];
    const int slot = lh[tid][e]++;
    const int idx = e*TOKENS + slot;
    tokidx[idx] = t;
    gatev[idx]  = tokp[t*3 + k];
    tokslot[t*3 + k] = idx;
  }
}

// ---------------- grouped GEMM 1: h = gelu(x @ W1 + b1) ----------------
// grid (16, MAXT), block 256. Tile 128x128, BK=64. R6-proven structure
// (asm MFMA, VGPR 64, 3 blocks/CU).

__global__ __launch_bounds__(256,3) void gemm1_kernel(
    const ushort* __restrict__ xb, const ushort* __restrict__ rW1T,
    const ushort* __restrict__ sW1T, const float* __restrict__ rb1,
    const float* __restrict__ sb1, const int* __restrict__ counts,
    const int* __restrict__ bases, const int* __restrict__ tokidx,
    const int* __restrict__ tile_e, const int* __restrict__ tile_by,
    const int* __restrict__ ntiles, ushort* __restrict__ h)
{
  const int ty = blockIdx.y;
  if (ty >= ntiles[0]) return;
  const int e = tile_e[ty], by = tile_by[ty], bx = blockIdx.x;
  const int cnt = (e < NE) ? counts[e] : TOKENS;

  __shared__ __align__(16) ushort lA[128*64];
  __shared__ __align__(16) ushort lB[128*64];

  const int tid = threadIdx.x, wave = tid >> 6, lane = tid & 63;
  const int wr = wave >> 1, wc = wave & 1;

  const ushort* Bp = (e < NE) ? (rW1T + ((size_t)e*DFR + (size_t)bx*128)*DM)
                              : (sW1T + ((size_t)(e-NE)*DFR + (size_t)bx*128)*DM);

  const ushort* srcA[4];
  const ushort* srcB[4];
  unsigned ldso[4];
  #pragma unroll
  for (int i=0;i<4;i++){
    const int rt = i*32 + wave*8 + (lane>>3);
    const int gr = by*128 + rt;
    const int tok = (e < NE) ? tokidx[e*TOKENS + (gr < cnt ? gr : cnt-1)] : gr;
    srcA[i] = xb + (size_t)tok*DM + (lane&7)*8;
    srcB[i] = Bp + (size_t)rt*DM + (lane&7)*8;
    ldso[i] = (unsigned)(i*4096 + wave*1024 + lane*16);
  }

  f32x4 acc[4][4];
  #pragma unroll
  for (int m=0;m<4;m++){
    #pragma unroll
    for (int n=0;n<4;n++){ acc[m][n] = (f32x4){0.f,0.f,0.f,0.f}; }
  }

  for (int k0=0; k0<DM; k0+=64){
    __syncthreads();
    #pragma unroll
    for (int i=0;i<4;i++){ gload16(srcA[i]+k0, (char*)lA + ldso[i]); }
    #pragma unroll
    for (int i=0;i<4;i++){ gload16(srcB[i]+k0, (char*)lB + ldso[i]); }
    __syncthreads();
    #pragma unroll
    for (int kk=0; kk<2; kk++){
      i32x4 af[4], bfr[4];
      #pragma unroll
      for (int m=0;m<4;m++){
        af[m] = *(const i32x4*)((const char*)lA + ((wr*64 + m*16 + (lane&15))*128 + kk*64 + (lane>>4)*16));
      }
      #pragma unroll
      for (int n=0;n<4;n++){
        bfr[n] = *(const i32x4*)((const char*)lB + ((wc*64 + n*16 + (lane&15))*128 + kk*64 + (lane>>4)*16));
      }
      #pragma unroll
      for (int m=0;m<4;m++){
        #pragma unroll
        for (int n=0;n<4;n++){ mfma_16x16x32_bf16(acc[m][n], af[m], bfr[n]); }
      }
    }
  }

  const int hb = bases[e];
  const float* b1p = (e < NE) ? (rb1 + e*DFR + bx*128) : (sb1 + (e-NE)*DFR + bx*128);
  #pragma unroll
  for (int m=0;m<4;m++){
    #pragma unroll
    for (int n=0;n<4;n++){
      const int c = wc*64 + n*16 + (lane & 15);
      const float bias = b1p[c];
      #pragma unroll
      for (int i=0;i<4;i++){
        const int r = wr*64 + m*16 + (lane>>4)*4 + i;
        float v = acc[m][n][i] + bias;
        h[(size_t)(hb + by*128 + r)*DFR + (size_t)bx*128 + c] = f2bf(gelu_fast(v));
      }
    }
  }
}

// ---------------- grouped GEMM 2: rout[row] = h @ W2 + b2 (bf16, no gate) ----
// grid (8, MAXT), block 256.

__global__ __launch_bounds__(256,3) void gemm2_kernel(
    const ushort* __restrict__ hbuf, const ushort* __restrict__ rW2T,
    const ushort* __restrict__ sW2T, const float* __restrict__ rb2,
    const float* __restrict__ sb2, const int* __restrict__ counts,
    const int* __restrict__ bases,
    const int* __restrict__ tile_e, const int* __restrict__ tile_by,
    const int* __restrict__ ntiles, ushort* __restrict__ rout)
{
  const int ty = blockIdx.y;
  if (ty >= ntiles[0]) return;
  const int e = tile_e[ty], by = tile_by[ty], bx = blockIdx.x;

  __shared__ __align__(16) ushort lA[128*64];
  __shared__ __align__(16) ushort lB[128*64];

  const int tid = threadIdx.x, wave = tid >> 6, lane = tid & 63;
  const int wr = wave >> 1, wc = wave & 1;

  const int hb = bases[e];
  const ushort* Ab = hbuf + (size_t)(hb + by*128)*DFR;
  const ushort* Bp; size_t ldb;
  if (e < NE){ Bp = rW2T + ((size_t)e*DM + (size_t)bx*128)*DFR; ldb = DFR; }
  else       { Bp = sW2T + (size_t)(bx*128)*DFF + (size_t)(e-NE)*DFR; ldb = DFF; }

  const ushort* srcA[4];
  const ushort* srcB[4];
  unsigned ldso[4];
  #pragma unroll
  for (int i=0;i<4;i++){
    const int rt = i*32 + wave*8 + (lane>>3);
    srcA[i] = Ab + (size_t)rt*DFR + (lane&7)*8;
    srcB[i] = Bp + (size_t)rt*ldb + (lane&7)*8;
    ldso[i] = (unsigned)(i*4096 + wave*1024 + lane*16);
  }

  f32x4 acc[4][4];
  #pragma unroll
  for (int m=0;m<4;m++){
    #pragma unroll
    for (int n=0;n<4;n++){ acc[m][n] = (f32x4){0.f,0.f,0.f,0.f}; }
  }

  for (int k0=0; k0<DFR; k0+=64){
    __syncthreads();
    #pragma unroll
    for (int i=0;i<4;i++){ gload16(srcA[i]+k0, (char*)lA + ldso[i]); }
    #pragma unroll
    for (int i=0;i<4;i++){ gload16(srcB[i]+k0, (char*)lB + ldso[i]); }
    __syncthreads();
    #pragma unroll
    for (int kk=0; kk<2; kk++){
      i32x4 af[4], bfr[4];
      #pragma unroll
      for (int m=0;m<4;m++){
        af[m] = *(const i32x4*)((const char*)lA + ((wr*64 + m*16 + (lane&15))*128 + kk*64 + (lane>>4)*16));
      }
      #pragma unroll
      for (int n=0;n<4;n++){
        bfr[n] = *(const i32x4*)((const char*)lB + ((wc*64 + n*16 + (lane&15))*128 + kk*64 + (lane>>4)*16));
      }
      #pragma unroll
      for (int m=0;m<4;m++){
        #pragma unroll
        for (int n=0;n<4;n++){ mfma_16x16x32_bf16(acc[m][n], af[m], bfr[n]); }
      }
    }
  }

  #pragma unroll
  for (int m=0;m<4;m++){
    #pragma unroll
    for (int n=0;n<4;n++){
      const int c  = wc*64 + n*16 + (lane & 15);
      const int cg = bx*128 + c;
      const float bias = (e < NE) ? rb2[e*DM + cg] : ((e == NE) ? sb2[cg] : 0.f);
      #pragma unroll
      for (int i=0;i<4;i++){
        const int r = wr*64 + m*16 + (lane>>4)*4 + i;
        rout[(size_t)(hb + by*128 + r)*DM + cg] = f2bf(acc[m][n][i] + bias);
      }
    }
  }
}

// ---------------- combine: out = x + sh0 + sh1 + sum_k gate_k * rout ----------

__global__ void combine_kernel(const float* __restrict__ x, const ushort* __restrict__ rout,
                               const int* __restrict__ bases, const int* __restrict__ tokslot,
                               const float* __restrict__ gatev, float* __restrict__ out)
{
  const int wave = threadIdx.x >> 6, lane = threadIdx.x & 63;
  const int token = blockIdx.x*4 + wave;
  const int d0 = lane*16;

  float acc[16];
  #pragma unroll
  for (int j=0;j<4;j++){
    float4 v = reinterpret_cast<const float4*>(x + (size_t)token*DM + d0)[j];
    acc[j*4+0]=v.x; acc[j*4+1]=v.y; acc[j*4+2]=v.z; acc[j*4+3]=v.w;
  }

  int   rows[5];
  float gs[5];
  rows[0] = bases[NE]   + token; gs[0] = 1.f;
  rows[1] = bases[NE+1] + token; gs[1] = 1.f;
  #pragma unroll
  for (int k=0;k<3;k++){
    const int idx = tokslot[token*3 + k];
    const int e = idx >> 12, s = idx & (TOKENS-1);
    rows[2+k] = bases[e] + s;
    gs[2+k] = gatev[idx];
  }

  #pragma unroll
  for (int q=0;q<5;q++){
    const float g = gs[q];
    const ushort* rp = rout + (size_t)rows[q]*DM + d0;
    #pragma unroll
    for (int hh=0;hh<2;hh++){
      i32x4 v = *reinterpret_cast<const i32x4*>(rp + hh*8);
      #pragma unroll
      for (int j=0;j<4;j++){
        const unsigned u = (unsigned)v[j];
        acc[hh*8 + j*2 + 0] += g * __uint_as_float(u << 16);
        acc[hh*8 + j*2 + 1] += g * __uint_as_float(u & 0xFFFF0000u);
      }
    }
  }

  #pragma unroll
  for (int j=0;j<4;j++){
    float4 v; v.x=acc[j*4+0]; v.y=acc[j*4+1]; v.z=acc[j*4+2]; v.w=acc[j*4+3];
    reinterpret_cast<float4*>(out + (size_t)token*DM + d0)[j] = v;
  }
}

// ---------------- launcher ----------------

extern "C" void kernel_launch(void* const* d_in, const int* in_sizes, int n_in,
                              void* d_out, int out_size, void* d_ws, size_t ws_size,
                              hipStream_t stream)
{
  (void)in_sizes; (void)n_in; (void)out_size; (void)ws_size;
  const float* x   = (const float*)d_in[0];
  const float* sW1 = (const float*)d_in[1];
  const float* sb1 = (const float*)d_in[2];
  const float* sW2 = (const float*)d_in[3];
  const float* sb2 = (const float*)d_in[4];
  const float* rW1 = (const float*)d_in[5];
  const float* rb1 = (const float*)d_in[6];
  const float* rW2 = (const float*)d_in[7];
  const float* rb2 = (const float*)d_in[8];
  const float* gW  = (const float*)d_in[9];
  const float* gb  = (const float*)d_in[10];
  float* out = (float*)d_out;

  char* ws = (char*)d_ws;
  ushort* xb   = (ushort*)(ws + 0);          //  8,388,608  x bf16 [4096][1024]
  ushort* sW1T = (ushort*)(ws + 8388608);    //  8,388,608  [4096][1024]
  ushort* sW2T = (ushort*)(ws + 16777216);   //  8,388,608  [1024][4096]
  ushort* rW1T = (ushort*)(ws + 25165824);   // 62,914,560  [15][2048][1024]
  ushort* rW2T = (ushort*)(ws + 88080384);   // 62,914,560  [15][1024][2048]
  ushort* hbuf = (ushort*)(ws + 150994944);  // 92,274,688  [22528][2048]
  // rout ALIASES rW1T's region: rW1T is dead after gemm1, rout written by gemm2.
  ushort* rout = (ushort*)(ws + 25165824);   // 46,137,344  [22528][1024]
  int*   counts  = (int*)(ws + 243269632);
  int*   bases   = (int*)(ws + 243269760);
  int*   tokidx  = (int*)(ws + 243270144);   // 15*4096 ints
  float* gatev   = (float*)(ws + 243515904); // 15*4096 floats
  int*   tokslot = (int*)(ws + 243761664);   // 4096*3 ints
  int*   tokexp  = (int*)(ws + 243810816);   // 4096*3 ints
  float* tokp    = (float*)(ws + 243859968); // 4096*3 floats
  int*   tile_e  = (int*)(ws + 243909120);   // MAXT ints
  int*   tile_by = (int*)(ws + 243910144);
  int*   ntiles  = (int*)(ws + 243911168);
  // total ~244 MB of workspace

  tcast_kernel<<<dim3(DFF/32, DM/32, 1),  dim3(32,8), 0, stream>>>(sW1, sW1T, DM, DFF);
  tcast_kernel<<<dim3(DM/32, DFF/32, 1),  dim3(32,8), 0, stream>>>(sW2, sW2T, DFF, DM);
  tcast_kernel<<<dim3(DFR/32, DM/32, NE), dim3(32,8), 0, stream>>>(rW1, rW1T, DM, DFR);
  tcast_kernel<<<dim3(DM/32, DFR/32, NE), dim3(32,8), 0, stream>>>(rW2, rW2T, DFR, DM);

  gate_kernel<<<dim3(TOKENS/4), dim3(256), 0, stream>>>(x, gW, gb, xb, tokexp, tokp);
  assign_kernel<<<dim3(1), dim3(256), 0, stream>>>(tokexp, tokp, counts, bases,
                                                   tokidx, gatev, tokslot,
                                                   tile_e, tile_by, ntiles);

  gemm1_kernel<<<dim3(16,MAXT), dim3(256), 0, stream>>>(
      xb, rW1T, sW1T, rb1, sb1, counts, bases, tokidx, tile_e, tile_by, ntiles, hbuf);
  gemm2_kernel<<<dim3(8,MAXT), dim3(256), 0, stream>>>(
      hbuf, rW2T, sW2T, rb2, sb2, counts, bases, tile_e, tile_by, ntiles, rout);
  combine_kernel<<<dim3(TOKENS/4), dim3(256), 0, stream>>>(
      x, rout, bases, tokslot, gatev, out);
}